// Round 28
// baseline (37.943 us; speedup 1.0000x reference)
//
#include <hip/hip_runtime.h>
#include <math.h>

// Problem constants (fixed by harness)
#define NN   128
#define TT   1024
#define SS   1024
#define H1D  512
#define H2D  128
#define OUTD 8
#define KQN  8      // layer-1 split-K chunks

// NUFFT constants (w=8 Gaussian validated R27: absmax 0.0039 = 1 bf16 ulp)
#define MR    2048
#define WHALF 3                    // window offsets k-3, k=0..7
#define ALPHA 0.5553604f           // pi/sqrt(32)
#define BETA  4.2368e-6f           // pi^2/(ALPHA*MR^2)
#define DSCALE 0.4204754f          // sqrt(ALPHA/pi)

// ws layout in floats
#define OFF_SUBT 0                          // [128 n][512 q][4 r] float2
#define OFF_P1   (NN*512*4*2)               // P1 [8 kq][128 n][512 j]
// end: OFF_P1 + 8*128*512 = 1048576

__device__ __forceinline__ float cos_rev(float r) { return __builtin_amdgcn_cosf(r); } // cos(2*pi*r)
__device__ __forceinline__ float sin_rev(float r) { return __builtin_amdgcn_sinf(r); } // sin(2*pi*r)

__device__ __forceinline__ float wave_sum(float v) {
#pragma unroll
    for (int off = 32; off > 0; off >>= 1) v += __shfl_xor(v, off, 64);
    return v;
}

// ---------------------------------------------------------------------------
// Kernel 1: FUSED residue-spread + 512-pt sub-FFT.
// R28 change vs R27 (sf ~10us, stall-dominated): FFT barrier count 9 -> 5 via
// mixed-radix Stockham DIF: 4 radix-4 stages + 1 twiddle-free radix-2.
// Convention matches the validated radix-2 kernel exactly:
//   u_q = DFT4 over p of src[tau + p*128];  dst[(4j+q)*m + i] = u_q * w_512^{q*j*m}
// (hand-verified at N=8 against the validated radix-2 factorization).
// All twiddle fractions q*j*m/512 < 1 -> no floorf reduction needed.
// ---------------------------------------------------------------------------
__global__ __launch_bounds__(512) void k_sf(const float* __restrict__ inp,
                                            float* __restrict__ ws) {
    const int r   = blockIdx.x;    // 0..3
    const int n   = blockIdx.y;    // 0..127
    const int tid = threadIdx.x;   // 0..511

    __shared__ float2 Ag[512];     // 4 KB
    __shared__ float2 Bg[512];     // 4 KB

    Ag[tid] = make_float2(0.f, 0.f);
    __syncthreads();

    const float* row = inp + (size_t)n * TT * 3;
#pragma unroll
    for (int pp = 0; pp < 2; ++pp) {
        const int t = pp * 512 + tid;
        const float x  = row[t * 3 + 0];
        const float d  = row[t * 3 + 2];
        const float df = d - floorf(d);            // exact for |d| < 2^23
        const float p512 = 512.0f * df;            // exact (pow2 scale)
        const float r512 = p512 - floorf(p512);
        const float cre = x * cos_rev(r512);
        const float cim = -x * sin_rev(r512);
        const float z  = df * 2048.0f;             // [0,2048)
        const int   j0 = (int)z;
        const float dl = z - (float)j0;
        const int k0 = (r + WHALF - j0 + 2048) & 3;
#pragma unroll
        for (int i = 0; i < 2; ++i) {
            const int   k = k0 + 4 * i;
            const float u = dl - (float)(k - WHALF);
            const float w = __expf(-ALPHA * u * u);
            const int  gi = (j0 + k - WHALF) & (MR - 1);
            const int   q = gi >> 2;               // gi == r (mod 4)
            atomicAdd(&Ag[q].x, w * cre);
            atomicAdd(&Ag[q].y, w * cim);
        }
    }
    __syncthreads();

    // ---- mixed-radix Stockham DIF: 4x radix-4 + 1x radix-2 (5 barriers) ----
    float2* src = Ag;
    float2* dst = Bg;
#pragma unroll
    for (int s4 = 0; s4 < 4; ++s4) {
        if (tid < 128) {
            const int m  = 1 << (2 * s4);
            const int j  = tid >> (2 * s4);
            const int i  = tid & (m - 1);
            const float base = (float)(j * m) * (1.0f / 512.0f);  // j*m/512 < 0.25
            const float2 s0 = src[tid];
            const float2 s1 = src[tid + 128];
            const float2 s2 = src[tid + 256];
            const float2 s3 = src[tid + 384];
            // DFT-4 over p (w_4 = -i)
            const float2 u0 = make_float2(s0.x + s1.x + s2.x + s3.x,
                                          s0.y + s1.y + s2.y + s3.y);
            const float2 u1 = make_float2(s0.x + s1.y - s2.x - s3.y,
                                          s0.y - s1.x - s2.y + s3.x);
            const float2 u2 = make_float2(s0.x - s1.x + s2.x - s3.x,
                                          s0.y - s1.y + s2.y - s3.y);
            const float2 u3 = make_float2(s0.x - s1.y - s2.x + s3.y,
                                          s0.y + s1.x - s2.y - s3.x);
            const float r1 = base, r2 = 2.0f * base, r3 = 3.0f * base;
            const float c1 = cos_rev(r1), v1 = sin_rev(r1);
            const float c2 = cos_rev(r2), v2 = sin_rev(r2);
            const float c3 = cos_rev(r3), v3 = sin_rev(r3);
            const int o = 4 * j * m + i;
            dst[o]       = u0;
            dst[o + m]   = make_float2(fmaf(u1.x, c1, u1.y * v1),
                                       fmaf(u1.y, c1, -u1.x * v1));
            dst[o + 2*m] = make_float2(fmaf(u2.x, c2, u2.y * v2),
                                       fmaf(u2.y, c2, -u2.x * v2));
            dst[o + 3*m] = make_float2(fmaf(u3.x, c3, u3.y * v3),
                                       fmaf(u3.y, c3, -u3.x * v3));
        }
        __syncthreads();
        float2* tmp = src; src = dst; dst = tmp;
    }
    // final radix-2 stage, m=256: j=0 -> twiddle-free (matches validated path)
    if (tid < 256) {
        const float2 a = src[tid];
        const float2 b = src[tid + 256];
        dst[tid]       = make_float2(a.x + b.x, a.y + b.y);
        dst[tid + 256] = make_float2(a.x - b.x, a.y - b.y);
    }
    __syncthreads();
    { float2* tmp = src; src = dst; dst = tmp; }

    float2* SUBT = (float2*)(ws + OFF_SUBT);
    SUBT[((size_t)n * 512 + tid) * 4 + r] = src[tid];
}

// ---------------------------------------------------------------------------
// Kernel 2: FUSED radix-4 combine+deconvolve+magnitude -> LDS tile -> l1p GEMM.
// R27 verbatim. Grid (8 kq, 4 jq, 16 nb) = 512 blocks x 256 thr.
// ---------------------------------------------------------------------------
__global__ __launch_bounds__(256) void k_cl1p(const float* __restrict__ W1,
                                              float* __restrict__ ws) {
    const int kq = blockIdx.x;   // 0..7
    const int jq = blockIdx.y;   // 0..3
    const int nb = blockIdx.z;   // 0..15
    const int tid = threadIdx.x;

    __shared__ float4 Al[8][32];  // 8 n-rows x 128 k
    float* Alf = (float*)Al;
    const float2* SUBT = (const float2*)(ws + OFF_SUBT);
#pragma unroll
    for (int i = 0; i < 4; ++i) {
        const int e    = i * 256 + tid;        // 0..1023
        const int rown = e >> 7;               // 0..7
        const int kk   = e & 127;
        const int n    = nb * 8 + rown;
        const int ss   = kq * 128 + kk;
        const int k    = (ss + 1536) & (MR - 1);
        const int km   = ss & 511;
        const float2* F = SUBT + ((size_t)n * 512 + km) * 4;
        float2 X = F[0];                       // r=0: w=1
        const float f1 = (float)k * (1.0f / 2048.0f);   // exact
#pragma unroll
        for (int rr = 1; rr < 4; ++rr) {
            const float2 Fr = F[rr];
            const float fr = (float)rr * f1;
            const float ff = fr - floorf(fr);  // exact
            const float cv = cos_rev(ff), sv = sin_rev(ff);  // w = cv - i*sv
            X.x = fmaf(Fr.x, cv, fmaf(Fr.y, sv, X.x));
            X.y = fmaf(Fr.y, cv, fmaf(-Fr.x, sv, X.y));
        }
        const int sp = ss - 512;
        const float D = DSCALE * __expf(BETA * (float)(sp * sp));
        Alf[e] = sqrtf(fmaf(X.x, X.x, X.y * X.y)) * D;
    }
    __syncthreads();

    // R19-verbatim l1p GEMM body
    const int jl = tid & 127, ng = tid >> 7;
    const int j = jq * 128 + jl;
    const float4* W1v = (const float4*)W1;
    float a0 = 0.f, a1 = 0.f, a2 = 0.f, a3 = 0.f;
#pragma unroll 4
    for (int k4 = 0; k4 < 32; ++k4) {
        const float4 w  = W1v[(size_t)j * 256 + kq * 32 + k4];
        const float4 x0 = Al[ng * 4 + 0][k4];
        const float4 x1 = Al[ng * 4 + 1][k4];
        const float4 x2 = Al[ng * 4 + 2][k4];
        const float4 x3 = Al[ng * 4 + 3][k4];
        a0 = fmaf(x0.x, w.x, fmaf(x0.y, w.y, fmaf(x0.z, w.z, fmaf(x0.w, w.w, a0))));
        a1 = fmaf(x1.x, w.x, fmaf(x1.y, w.y, fmaf(x1.z, w.z, fmaf(x1.w, w.w, a1))));
        a2 = fmaf(x2.x, w.x, fmaf(x2.y, w.y, fmaf(x2.z, w.z, fmaf(x2.w, w.w, a2))));
        a3 = fmaf(x3.x, w.x, fmaf(x3.y, w.y, fmaf(x3.z, w.z, fmaf(x3.w, w.w, a3))));
    }
    float* P1 = ws + OFF_P1;
    const float acc[4] = {a0, a1, a2, a3};
#pragma unroll
    for (int i = 0; i < 4; ++i)
        P1[((size_t)(kq * NN + nb * 8 + ng * 4 + i)) * H1D + j] = acc[i];
}

// ---------------------------------------------------------------------------
// Kernel 3: FUSED MLP tail per batch n (l1c + l2 + l3) — R27 verbatim.
// 128 blocks x 1024 thr.
// ---------------------------------------------------------------------------
__global__ __launch_bounds__(1024) void k_mlp(const float* __restrict__ b1,
                                              const float* __restrict__ W2,
                                              const float* __restrict__ b2,
                                              const float* __restrict__ W3,
                                              const float* __restrict__ b3,
                                              const float* __restrict__ ws,
                                              float* __restrict__ out) {
    const int n   = blockIdx.x;
    const int tid = threadIdx.x;
    const int wid = tid >> 6, lane = tid & 63;

    __shared__ float h1L[H1D];
    __shared__ float h2L[H2D];

    if (tid < H1D) {
        const int j = tid;
        float s = b1[j];
#pragma unroll
        for (int kq = 0; kq < KQN; ++kq)
            s += ws[OFF_P1 + ((size_t)kq * NN + n) * H1D + j];
        h1L[j] = 1.0f / (1.0f + __expf(-s));
    }
    __syncthreads();

    // layer 2: wave wid handles j = wid*8 .. wid*8+7
    {
        const float4* H1v = (const float4*)h1L;
        const float4 ha = H1v[lane], hb = H1v[64 + lane];
#pragma unroll
        for (int q = 0; q < 8; ++q) {
            const int j = wid * 8 + q;
            const float4* W2v = (const float4*)W2 + (size_t)j * 128;
            const float4 wa = W2v[lane], wb = W2v[64 + lane];
            float a = fmaf(wa.x, ha.x, fmaf(wa.y, ha.y, fmaf(wa.z, ha.z, wa.w * ha.w)));
            a = fmaf(wb.x, hb.x, fmaf(wb.y, hb.y, fmaf(wb.z, hb.z, fmaf(wb.w, hb.w, a))));
            a = wave_sum(a);
            if (lane == 0) h2L[j] = 1.0f / (1.0f + __expf(-(a + b2[j])));
        }
    }
    __syncthreads();

    // layer 3: waves 0..7, one output each
    if (wid < OUTD) {
        const float2 w = ((const float2*)W3)[wid * 64 + lane];
        const float2 h = ((const float2*)h2L)[lane];
        float a = fmaf(w.x, h.x, w.y * h.y);
        a = wave_sum(a);
        if (lane == 0) out[n * OUTD + wid] = a + b3[wid];
    }
}

extern "C" void kernel_launch(void* const* d_in, const int* in_sizes, int n_in,
                              void* d_out, int out_size, void* d_ws, size_t ws_size,
                              hipStream_t stream) {
    (void)in_sizes; (void)n_in; (void)out_size; (void)ws_size;
    const float* inp = (const float*)d_in[0];
    const float* W1  = (const float*)d_in[1];
    const float* b1  = (const float*)d_in[2];
    const float* W2  = (const float*)d_in[3];
    const float* b2  = (const float*)d_in[4];
    const float* W3  = (const float*)d_in[5];
    const float* b3  = (const float*)d_in[6];
    float* out = (float*)d_out;
    float* ws  = (float*)d_ws;

    k_sf  <<<dim3(4, NN),    dim3(512),  0, stream>>>(inp, ws);
    k_cl1p<<<dim3(8, 4, 16), dim3(256),  0, stream>>>(W1, ws);
    k_mlp <<<dim3(NN),       dim3(1024), 0, stream>>>(b1, W2, b2, W3, b3, ws, out);
}